// Round 17
// baseline (448.146 us; speedup 1.0000x reference)
//
#include <hip/hip_runtime.h>
#include <hip/hip_bf16.h>

constexpr int DIN = 16;
constexpr int D   = 256;
constexpr int NH  = 8;
constexpr int NC  = 32;
constexpr int MC  = 200;
constexpr int NT  = 8;
constexpr int BG  = 16;
constexpr int NL  = 6;
constexpr int PS  = 16;   // pool slices per graph
constexpr float NEG = 0.2f;

typedef __attribute__((ext_vector_type(8))) short bfrag;
typedef __attribute__((ext_vector_type(4))) float f32x4;

__device__ inline unsigned short f2bf(float f) {
    unsigned int u = __float_as_uint(f);
    u += 0x7FFFu + ((u >> 16) & 1u);
    return (unsigned short)(u >> 16);
}
__device__ inline float bf2f(unsigned short u) {
    return __uint_as_float((unsigned int)u << 16);
}

__device__ inline float dot_ilp(const float* g, const float* __restrict__ W, int K, int ldw, int t) {
    float a0 = 0.f, a1 = 0.f, a2 = 0.f, a3 = 0.f;
    for (int k = 0; k < K; k += 4) {
        a0 = fmaf(g[k + 0], W[(k + 0) * ldw + t], a0);
        a1 = fmaf(g[k + 1], W[(k + 1) * ldw + t], a1);
        a2 = fmaf(g[k + 2], W[(k + 2) * ldw + t], a2);
        a3 = fmaf(g[k + 3], W[(k + 3) * ldw + t], a3);
    }
    return (a0 + a1) + (a2 + a3);
}

// ---------------- device helpers ----------------

__device__ inline void enc_node(const float* x, const float* W, const float* b, const float* ls,
                                const float* lb, float* h, int n, int lane) {
    int c4 = lane * 4;
    float xs[DIN];
#pragma unroll
    for (int k = 0; k < DIN; k += 4) {
        float4 xv = *(const float4*)&x[n * DIN + k];
        xs[k] = xv.x; xs[k + 1] = xv.y; xs[k + 2] = xv.z; xs[k + 3] = xv.w;
    }
    float4 a = *(const float4*)&b[c4];
#pragma unroll
    for (int k = 0; k < DIN; k++) {
        float4 wv = *(const float4*)&W[k * D + c4];
        a.x = fmaf(xs[k], wv.x, a.x);
        a.y = fmaf(xs[k], wv.y, a.y);
        a.z = fmaf(xs[k], wv.z, a.z);
        a.w = fmaf(xs[k], wv.w, a.w);
    }
    float s = a.x + a.y + a.z + a.w;
#pragma unroll
    for (int msk = 1; msk <= 32; msk <<= 1) s += __shfl_xor(s, msk);
    float mu = s * (1.f / D);
    float4 dv = make_float4(a.x - mu, a.y - mu, a.z - mu, a.w - mu);
    float v2 = dv.x * dv.x + dv.y * dv.y + dv.z * dv.z + dv.w * dv.w;
#pragma unroll
    for (int msk = 1; msk <= 32; msk <<= 1) v2 += __shfl_xor(v2, msk);
    float rstd = rsqrtf(v2 * (1.f / D) + 1e-5f);
    float4 lsv = *(const float4*)&ls[c4];
    float4 lbv = *(const float4*)&lb[c4];
    float4 y = make_float4(fmaxf(dv.x * rstd * lsv.x + lbv.x, 0.f),
                           fmaxf(dv.y * rstd * lsv.y + lbv.y, 0.f),
                           fmaxf(dv.z * rstd * lsv.z + lbv.z, 0.f),
                           fmaxf(dv.w * rstd * lsv.w + lbv.w, 0.f));
    *(float4*)&h[(size_t)n * D + c4] = y;
}

// MFMA GEMM on a 16-row tile, executed by ONE wave handling ONE 16-col tile (ctg).
__device__ inline void gemm_one_ct(const unsigned short (*As)[264],
                                   const unsigned short* WpL, const unsigned short* WpR,
                                   const float* bl, const float* br,
                                   unsigned short* xl, unsigned short* xr,
                                   int N, int nb, int ctg, int lane) {
    int m = lane & 15, q = lane >> 4;
    float bLv = bl[ctg * 16 + m];
    float bRv = br[ctg * 16 + m];
    f32x4 accL = (f32x4){bLv, bLv, bLv, bLv};
    f32x4 accR = (f32x4){bRv, bRv, bRv, bRv};
#pragma unroll
    for (int ks = 0; ks < 8; ks++) {
        bfrag af = *(const bfrag*)&As[m][ks * 32 + q * 8];
        size_t off = (((size_t)ctg * 8 + ks) * 64 + lane) * 8;
        bfrag bL = *(const bfrag*)&WpL[off];
        bfrag bR = *(const bfrag*)&WpR[off];
        accL = __builtin_amdgcn_mfma_f32_16x16x32_bf16(af, bL, accL, 0, 0, 0);
        accR = __builtin_amdgcn_mfma_f32_16x16x32_bf16(af, bR, accR, 0, 0, 0);
    }
    int colg = ctg * 16 + m;
#pragma unroll
    for (int reg = 0; reg < 4; reg++) {
        int row = nb + q * 4 + reg;
        if (row < N) {
            xl[(size_t)row * D + colg] = f2bf(accL[reg]);
            xr[(size_t)row * D + colg] = f2bf(accR[reg]);
        }
    }
}

// 4-wave variant (wave w owns col-tiles w*4..w*4+3)
__device__ inline void gemm_core(const unsigned short (*As)[264],
                                 const unsigned short* WpL, const unsigned short* WpR,
                                 const float* bl, const float* br,
                                 unsigned short* xl, unsigned short* xr, int N, int nb, int T) {
    int lane = T & 63, w = T >> 6;
#pragma unroll
    for (int ct = 0; ct < 4; ct++)
        gemm_one_ct(As, WpL, WpR, bl, br, xl, xr, N, nb, w * 4 + ct, lane);
}

__device__ inline void repack_attn_one(const float* Wl, const float* Wr, unsigned short* Wp, int tid) {
    int lane = tid & 63;
    int r1 = tid >> 6;
    int ks = r1 & 7;
    int r2 = r1 >> 3;
    int ct = r2 & 15;
    int mi = r2 >> 4;
    int layer = mi >> 1, mat = mi & 1;
    const float* W = (mat == 0 ? Wl : Wr) + (size_t)layer * D * D;
    int n = ct * 16 + (lane & 15);
    int kb = ks * 32 + (lane >> 4) * 8;
    size_t base = (((size_t)(mi * 16 + ct) * 8 + ks) * 64 + lane) * 8;
#pragma unroll
    for (int j = 0; j < 8; j++) Wp[base + j] = f2bf(W[(size_t)(kb + j) * D + n]);
}

__device__ inline void repack_gen_one(const float* W, unsigned short* Wp, int K, int NCOL, int nks, int tid) {
    int lane = tid & 63;
    int r = tid >> 6;
    int ks = r % nks;
    int ct = r / nks;
    int n = ct * 16 + (lane & 15);
    int kb = ks * 32 + (lane >> 4) * 8;
    size_t base = (((size_t)ct * nks + ks) * 64 + lane) * 8;
#pragma unroll
    for (int j = 0; j < 8; j++) {
        int k = kb + j;
        Wp[base + j] = (n < NCOL && k < K) ? f2bf(W[(size_t)k * NCOL + n]) : (unsigned short)0;
    }
}

// ---------------- kernels (18 dispatches) ----------------

__global__ __launch_bounds__(256) void init_enc_k(const float* __restrict__ x, const float* __restrict__ W,
                                                  const float* __restrict__ b, const float* __restrict__ ls,
                                                  const float* __restrict__ lb, float* __restrict__ h,
                                                  int* __restrict__ deg, int N) {
    int gid = blockIdx.x * 256 + threadIdx.x;
    if (gid < N) deg[gid] = 1;
    int lane = threadIdx.x & 63;
    int n = blockIdx.x * 4 + (threadIdx.x >> 6);
    if (n < N) enc_node(x, W, b, ls, lb, h, n, lane);
}

__global__ __launch_bounds__(256) void count_repack_k(const int* __restrict__ dst, int* __restrict__ deg, int E,
                                                      const float* __restrict__ Wl, const float* __restrict__ Wr,
                                                      unsigned short* __restrict__ Wp,
                                                      const float* __restrict__ cW1, unsigned short* __restrict__ cW1p,
                                                      const float* __restrict__ cW2, unsigned short* __restrict__ cW2p,
                                                      const float* __restrict__ cW3, unsigned short* __restrict__ cW3p) {
    int gid = blockIdx.x * 256 + threadIdx.x;
    if (gid < E) atomicAdd(&deg[dst[gid]], 1);
    if (gid < NL * 2 * 16 * 8 * 64) repack_attn_one(Wl, Wr, Wp, gid);
    if (gid < 16 * 8 * 64) repack_gen_one(cW1, cW1p, D, D, 8, gid);
    if (gid < 8 * 8 * 64)  repack_gen_one(cW2, cW2p, D, 128, 8, gid);
    if (gid < 13 * 4 * 64) repack_gen_one(cW3, cW3p, 128, MC, 4, gid);
}

__global__ __launch_bounds__(1024) void scan_k(const int* __restrict__ deg, int* __restrict__ row_ptr,
                                               int* __restrict__ fill, int N) {
    __shared__ int sd[1024];
    int t = threadIdx.x;
    int chunk = (N + 1023) >> 10;
    int lo = t * chunk, hi = min(lo + chunk, N);
    int s = 0;
    for (int i = lo; i < hi; i++) s += deg[i];
    sd[t] = s;
    __syncthreads();
    for (int off = 1; off < 1024; off <<= 1) {
        int v = (t >= off) ? sd[t - off] : 0;
        __syncthreads();
        sd[t] += v;
        __syncthreads();
    }
    int run = (t > 0) ? sd[t - 1] : 0;
    for (int i = lo; i < hi; i++) {
        row_ptr[i] = run; fill[i] = run;
        run += deg[i];
    }
    if (t == 1023) row_ptr[N] = sd[1023];
}

__global__ __launch_bounds__(256) void scatter_gemm0_k(const int* __restrict__ src, const int* __restrict__ dst,
                                                       int* __restrict__ fill, int* __restrict__ col, int E, int N,
                                                       const float* __restrict__ h,
                                                       const unsigned short* __restrict__ WpL,
                                                       const unsigned short* __restrict__ WpR,
                                                       const float* __restrict__ bl, const float* __restrict__ br,
                                                       unsigned short* __restrict__ xl, unsigned short* __restrict__ xr) {
    __shared__ unsigned short As[16][264];
    int T = threadIdx.x;
    int tt = blockIdx.x;
    int ntiles = (N + 15) >> 4;
    if (tt < ntiles) {
        int nb = tt * 16;
#pragma unroll
        for (int r = 0; r < 16; r++) {
            int row = nb + r;
            float v = (row < N) ? h[(size_t)row * D + T] : 0.f;
            As[r][T] = f2bf(v);
        }
        __syncthreads();
        gemm_core(As, WpL, WpR, bl, br, xl, xr, N, nb, T);
    }
    for (int e = blockIdx.x * 256 + T; e < E + N; e += gridDim.x * 256) {
        if (e < E) {
            int p = atomicAdd(&fill[dst[e]], 1);
            col[p] = src[e];
        } else {
            int n = e - E;
            int p = atomicAdd(&fill[n], 1);
            col[p] = n;
        }
    }
}

// standalone per-layer GEMM: 16 nodes/block, 256 threads (round-8 form, ~8-10 µs)
__global__ __launch_bounds__(256) void gemm_k(const float* __restrict__ h,
                                              const unsigned short* __restrict__ WpL,
                                              const unsigned short* __restrict__ WpR,
                                              const float* __restrict__ bl, const float* __restrict__ br,
                                              unsigned short* __restrict__ xl, unsigned short* __restrict__ xr,
                                              int N) {
    __shared__ unsigned short As[16][264];
    int T = threadIdx.x;
    int nb = blockIdx.x * 16;
#pragma unroll
    for (int r = 0; r < 16; r++) {
        int row = nb + r;
        float v = (row < N) ? h[(size_t)row * D + T] : 0.f;
        As[r][T] = f2bf(v);
    }
    __syncthreads();
    gemm_core(As, WpL, WpR, bl, br, xl, xr, N, nb, T);
}

// split-edge attention: ONE NODE per 256-thread block; 4 waves each take stride-4 edge subsets,
// merge online-softmax partials (m,l,acc) in LDS; wave 0 runs the LN/ELU/residual epilogue.
__global__ __launch_bounds__(256) void attn_k(const unsigned short* __restrict__ xl,
                                              const unsigned short* __restrict__ xr,
                                              const int* __restrict__ row_ptr, const int* __restrict__ col,
                                              const float* __restrict__ att, const float* __restrict__ gb,
                                              const float* __restrict__ gls, const float* __restrict__ glb,
                                              float* __restrict__ h, int layer, int N) {
    int n = blockIdx.x;
    int T = threadIdx.x;
    int lane = T & 63, w = T >> 6;
    int c4 = lane * 4;
    __shared__ float pm[4][64], pl[4][64];
    __shared__ float pax[4][64], pay[4][64], paz[4][64], paw[4][64];

    ushort4 xr4 = *(const ushort4*)&xr[(size_t)n * D + c4];
    float4 xrv = make_float4(bf2f(xr4.x), bf2f(xr4.y), bf2f(xr4.z), bf2f(xr4.w));
    float4 av  = *(const float4*)&att[c4];
    int beg = row_ptr[n], deg = row_ptr[n + 1] - beg;
    int myc = col[beg + min(lane, deg - 1)];

    float m = -3.0e38f, l = 0.f;
    float4 acc = make_float4(0.f, 0.f, 0.f, 0.f);
    auto loadx = [&](int i) -> ushort4 {            // absolute edge index; wave-uniform guard
        if (i < deg) {
            int s = (i < 64) ? __shfl(myc, i) : col[beg + i];
            return *(const ushort4*)&xl[(size_t)s * D + c4];
        }
        return make_ushort4(0, 0, 0, 0);
    };
    auto step = [&](ushort4 x4) {
        float4 xlv = make_float4(bf2f(x4.x), bf2f(x4.y), bf2f(x4.z), bf2f(x4.w));
        float sx = xlv.x + xrv.x; sx = sx > 0.f ? sx : NEG * sx;
        float sy = xlv.y + xrv.y; sy = sy > 0.f ? sy : NEG * sy;
        float sz = xlv.z + xrv.z; sz = sz > 0.f ? sz : NEG * sz;
        float sw = xlv.w + xrv.w; sw = sw > 0.f ? sw : NEG * sw;
        float z = av.x * sx + av.y * sy + av.z * sz + av.w * sw;
        z += __shfl_xor(z, 1); z += __shfl_xor(z, 2); z += __shfl_xor(z, 4);
        float mn = fmaxf(m, z);
        float sc = __expf(m - mn);
        float p  = __expf(z - mn);
        l = l * sc + p;
        acc.x = acc.x * sc + p * xlv.x;
        acc.y = acc.y * sc + p * xlv.y;
        acc.z = acc.z * sc + p * xlv.z;
        acc.w = acc.w * sc + p * xlv.w;
        m = mn;
    };
    // wave w handles edges w, w+4, w+8, ... : chain length ~deg/4, 2-deep prefetch
    int cnt = (deg > w) ? ((deg - 1 - w) / 4 + 1) : 0;   // wave-uniform
    ushort4 b0 = loadx(w), b1 = loadx(w + 4);
    for (int j = 0; j < cnt; j += 2) {
        ushort4 q0 = loadx(w + 4 * (j + 2));
        ushort4 q1 = loadx(w + 4 * (j + 3));
        step(b0);
        if (j + 1 < cnt) step(b1);
        b0 = q0; b1 = q1;
    }
    pm[w][lane] = m; pl[w][lane] = l;
    pax[w][lane] = acc.x; pay[w][lane] = acc.y; paz[w][lane] = acc.z; paw[w][lane] = acc.w;
    __syncthreads();
    if (w == 0) {
        // merge 4 partials (empty subsets have m=-3e38, l=0 -> weight underflows to 0)
        float M = fmaxf(fmaxf(pm[0][lane], pm[1][lane]), fmaxf(pm[2][lane], pm[3][lane]));
        float L = 0.f;
        float4 A = make_float4(0.f, 0.f, 0.f, 0.f);
#pragma unroll
        for (int k = 0; k < 4; k++) {
            float e = __expf(pm[k][lane] - M);
            L += pl[k][lane] * e;
            A.x += pax[k][lane] * e;
            A.y += pay[k][lane] * e;
            A.z += paz[k][lane] * e;
            A.w += paw[k][lane] * e;
        }
        float4 gbv = *(const float4*)&gb[c4];
        float rl = 1.f / L;
        float4 o = make_float4(A.x * rl + gbv.x, A.y * rl + gbv.y,
                               A.z * rl + gbv.z, A.w * rl + gbv.w);
        float s = o.x + o.y + o.z + o.w;
#pragma unroll
        for (int msk = 1; msk <= 32; msk <<= 1) s += __shfl_xor(s, msk);
        float mu = s * (1.f / D);
        float4 dv = make_float4(o.x - mu, o.y - mu, o.z - mu, o.w - mu);
        float v2 = dv.x * dv.x + dv.y * dv.y + dv.z * dv.z + dv.w * dv.w;
#pragma unroll
        for (int msk = 1; msk <= 32; msk <<= 1) v2 += __shfl_xor(v2, msk);
        float rstd = rsqrtf(v2 * (1.f / D) + 1e-5f);
        float4 glsv = *(const float4*)&gls[c4];
        float4 glbv = *(const float4*)&glb[c4];
        float y0 = dv.x * rstd * glsv.x + glbv.x;
        float y1 = dv.y * rstd * glsv.y + glbv.y;
        float y2 = dv.z * rstd * glsv.z + glbv.z;
        float y3 = dv.w * rstd * glsv.w + glbv.w;
        y0 = y0 > 0.f ? y0 : expm1f(y0);
        y1 = y1 > 0.f ? y1 : expm1f(y1);
        y2 = y2 > 0.f ? y2 : expm1f(y2);
        y3 = y3 > 0.f ? y3 : expm1f(y3);
        float4 prev = make_float4(0.f, 0.f, 0.f, 0.f);
        if (layer > 0) prev = *(const float4*)&h[(size_t)n * D + c4];
        *(float4*)&h[(size_t)n * D + c4] =
            make_float4(prev.x + y0, prev.y + y1, prev.z + y2, prev.w + y3);
    }
}

// fused color-head MFMA MLP: 16 nodes/block, 256 threads (round-8 form)
__global__ __launch_bounds__(256) void color_mfma_k(const float* __restrict__ h,
                                                    const unsigned short* __restrict__ W1p, const float* __restrict__ b1,
                                                    const unsigned short* __restrict__ W2p, const float* __restrict__ b2,
                                                    const unsigned short* __restrict__ W3p, const float* __restrict__ b3,
                                                    float* __restrict__ out, int N) {
    int T = threadIdx.x;
    int lane = T & 63;
    int w = T >> 6;
    int nb = blockIdx.x * 16;
    __shared__ unsigned short As[16][264];
    __shared__ unsigned short Zs[16][264];
#pragma unroll
    for (int r = 0; r < 16; r++) {
        int row = nb + r;
        float v = (row < N) ? h[(size_t)row * D + T] : 0.f;
        As[r][T] = f2bf(v);
    }
    __syncthreads();
    int m = lane & 15, q = lane >> 4;
    {
        f32x4 acc[4];
#pragma unroll
        for (int ct = 0; ct < 4; ct++) {
            float bv = b1[(w * 4 + ct) * 16 + m];
            acc[ct] = (f32x4){bv, bv, bv, bv};
        }
#pragma unroll 2
        for (int ks = 0; ks < 8; ks++) {
            bfrag af = *(const bfrag*)&As[m][ks * 32 + q * 8];
#pragma unroll
            for (int ct = 0; ct < 4; ct++) {
                int ctg = w * 4 + ct;
                bfrag bf = *(const bfrag*)&W1p[(((size_t)ctg * 8 + ks) * 64 + lane) * 8];
                acc[ct] = __builtin_amdgcn_mfma_f32_16x16x32_bf16(af, bf, acc[ct], 0, 0, 0);
            }
        }
#pragma unroll
        for (int ct = 0; ct < 4; ct++) {
            int colg = (w * 4 + ct) * 16 + m;
#pragma unroll
            for (int reg = 0; reg < 4; reg++)
                Zs[q * 4 + reg][colg] = f2bf(fmaxf(acc[ct][reg], 0.f));
        }
    }
    __syncthreads();
    {
        f32x4 acc[2];
#pragma unroll
        for (int ct = 0; ct < 2; ct++) {
            float bv = b2[(w * 2 + ct) * 16 + m];
            acc[ct] = (f32x4){bv, bv, bv, bv};
        }
#pragma unroll 2
        for (int ks = 0; ks < 8; ks++) {
            bfrag af = *(const bfrag*)&Zs[m][ks * 32 + q * 8];
#pragma unroll
            for (int ct = 0; ct < 2; ct++) {
                int ctg = w * 2 + ct;
                bfrag bf = *(const bfrag*)&W2p[(((size_t)ctg * 8 + ks) * 64 + lane) * 8];
                acc[ct] = __builtin_amdgcn_mfma_f32_16x16x32_bf16(af, bf, acc[ct], 0, 0, 0);
            }
        }
        __syncthreads();
#pragma unroll
        for (int ct = 0; ct < 2; ct++) {
            int colg = (w * 2 + ct) * 16 + m;
#pragma unroll
            for (int reg = 0; reg < 4; reg++)
                As[q * 4 + reg][colg] = f2bf(fmaxf(acc[ct][reg], 0.f));
        }
    }
    __syncthreads();
    for (int ctg = w; ctg < 13; ctg += 4) {
        int colg = ctg * 16 + m;
        float bv = (colg < MC) ? b3[colg] : 0.f;
        f32x4 acc = (f32x4){bv, bv, bv, bv};
#pragma unroll
        for (int ks = 0; ks < 4; ks++) {
            bfrag af = *(const bfrag*)&As[m][ks * 32 + q * 8];
            bfrag bf = *(const bfrag*)&W3p[(((size_t)ctg * 4 + ks) * 64 + lane) * 8];
            acc = __builtin_amdgcn_mfma_f32_16x16x32_bf16(af, bf, acc, 0, 0, 0);
        }
#pragma unroll
        for (int reg = 0; reg < 4; reg++) {
            int row = nb + q * 4 + reg;
            if (row < N && colg < MC) out[(size_t)row * MC + colg] = acc[reg];
        }
    }
}

// pooling stage 1
__global__ __launch_bounds__(256) void pool_k(const float* __restrict__ h, const int* __restrict__ batch,
                                              float* __restrict__ psum, float* __restrict__ pmax,
                                              int* __restrict__ cnt, int N) {
    int b = blockIdx.x;
    int sl = blockIdx.y;
    int c = threadIdx.x;
    int lo = 0, hi = N;
    while (lo < hi) { int mid = (lo + hi) >> 1; if (batch[mid] < b) lo = mid + 1; else hi = mid; }
    int s0 = lo;
    lo = 0; hi = N;
    while (lo < hi) { int mid = (lo + hi) >> 1; if (batch[mid] < b + 1) lo = mid + 1; else hi = mid; }
    int s1 = lo;
    int len = s1 - s0;
    int chunk = (len + PS - 1) / PS;
    int n0 = s0 + sl * chunk;
    int n1 = min(n0 + chunk, s1);
    float sum = 0.f, mx = -3.0e38f;
    for (int n = n0; n < n1; n++) {
        float v = h[(size_t)n * D + c];
        sum += v;
        mx = fmaxf(mx, v);
    }
    psum[(size_t)(b * PS + sl) * D + c] = sum;
    pmax[(size_t)(b * PS + sl) * D + c] = mx;
    if (c == 0 && sl == 0) cnt[b] = len;
}

// graph heads
__global__ __launch_bounds__(256) void heads_k(const float* __restrict__ psum, const float* __restrict__ pmax,
                                               const int* __restrict__ cnt,
                                               const float* __restrict__ chW1, const float* __restrict__ chb1,
                                               const float* __restrict__ chW2, const float* __restrict__ chb2,
                                               const float* __restrict__ chW3, const float* __restrict__ chb3,
                                               const float* __restrict__ tW1, const float* __restrict__ tb1,
                                               const float* __restrict__ tW2, const float* __restrict__ tb2,
                                               const float* __restrict__ dW1, const float* __restrict__ db1,
                                               const float* __restrict__ dW2, const float* __restrict__ db2,
                                               float* __restrict__ out_ch, float* __restrict__ out_t,
                                               float* __restrict__ out_d) {
    int b = blockIdx.x, sec = blockIdx.y, t = threadIdx.x;
    __shared__ float g[2 * D];
    __shared__ float z1[D];
    __shared__ float z2[128];
    float sum = 0.f, mx = -3.0e38f;
#pragma unroll
    for (int sl = 0; sl < PS; sl++) {
        sum += psum[(size_t)(b * PS + sl) * D + t];
        mx = fmaxf(mx, pmax[(size_t)(b * PS + sl) * D + t]);
    }
    int cn = cnt[b];
    float c = fmaxf((float)cn, 1.f);
    g[t] = sum / c;
    g[D + t] = (cn > 0) ? mx : 0.f;
    __syncthreads();
    if (sec == 0) {
        z1[t] = fmaxf(chb1[t] + dot_ilp(g, chW1, 2 * D, D, t), 0.f);
        __syncthreads();
        if (t < 128) z2[t] = fmaxf(chb2[t] + dot_ilp(z1, chW2, D, 128, t), 0.f);
        __syncthreads();
        if (t < MC) out_ch[b * MC + t] = chb3[t] + dot_ilp(z2, chW3, 128, MC, t);
    } else if (sec == 1) {
        if (t < 128) z1[t] = fmaxf(tb1[t] + dot_ilp(g, tW1, 2 * D, 128, t), 0.f);
        __syncthreads();
        if (t < NT) out_t[b * NT + t] = tb2[t] + dot_ilp(z1, tW2, 128, NT, t);
    } else {
        if (t < 64) z1[t] = fmaxf(db1[t] + dot_ilp(g, dW1, 2 * D, 64, t), 0.f);
        __syncthreads();
        if (t == 0) {
            float a = db2[0] + dot_ilp(z1, dW2, 64, 1, 0);
            out_d[b] = 100.f / (1.f + __expf(-a));
        }
    }
}

// ----------------------------------------------------------------
extern "C" void kernel_launch(void* const* d_in, const int* in_sizes, int n_in,
                              void* d_out, int out_size, void* d_ws, size_t ws_size,
                              hipStream_t stream) {
    const float* x     = (const float*)d_in[0];
    const int*   ei    = (const int*)d_in[1];
    const int*   batch = (const int*)d_in[2];
    const float* encW  = (const float*)d_in[3];
    const float* encb  = (const float*)d_in[4];
    const float* encls = (const float*)d_in[5];
    const float* enclb = (const float*)d_in[6];
    const float* Wl    = (const float*)d_in[7];
    const float* bl    = (const float*)d_in[8];
    const float* Wr    = (const float*)d_in[9];
    const float* br    = (const float*)d_in[10];
    const float* att   = (const float*)d_in[11];
    const float* gb    = (const float*)d_in[12];
    const float* gls   = (const float*)d_in[13];
    const float* glb   = (const float*)d_in[14];
    const float* cW1   = (const float*)d_in[15];
    const float* cb1   = (const float*)d_in[16];
    const float* cW2   = (const float*)d_in[17];
    const float* cb2   = (const float*)d_in[18];
    const float* cW3   = (const float*)d_in[19];
    const float* cb3   = (const float*)d_in[20];
    const float* chW1  = (const float*)d_in[21];
    const float* chb1  = (const float*)d_in[22];
    const float* chW2  = (const float*)d_in[23];
    const float* chb2  = (const float*)d_in[24];
    const float* chW3  = (const float*)d_in[25];
    const float* chb3  = (const float*)d_in[26];
    const float* tW1   = (const float*)d_in[27];
    const float* tb1   = (const float*)d_in[28];
    const float* tW2   = (const float*)d_in[29];
    const float* tb2   = (const float*)d_in[30];
    const float* dW1   = (const float*)d_in[31];
    const float* db1   = (const float*)d_in[32];
    const float* dW2   = (const float*)d_in[33];
    const float* db2   = (const float*)d_in[34];

    const int N = in_sizes[0] / DIN;
    const int E = in_sizes[1] / 2;
    const int* esrc = ei;
    const int* edst = ei + E;

    char* p = (char*)d_ws;
    auto carve = [&](size_t bytes) { char* r = p; p += (bytes + 255) & ~(size_t)255; return r; };
    int*            row_ptr = (int*)carve((size_t)(N + 1) * 4);
    int*            fill    = (int*)carve((size_t)N * 4);
    int*            deg     = (int*)carve((size_t)N * 4);
    int*            cnt     = (int*)carve((size_t)BG * 4);
    float*          psum    = (float*)carve((size_t)BG * PS * D * 4);
    float*          pmax    = (float*)carve((size_t)BG * PS * D * 4);
    int*            col     = (int*)carve((size_t)(E + N) * 4);
    unsigned short* Wp      = (unsigned short*)carve((size_t)NL * 2 * 65536 * 2);
    unsigned short* cW1p    = (unsigned short*)carve((size_t)16 * 8 * 64 * 8 * 2);
    unsigned short* cW2p    = (unsigned short*)carve((size_t)8 * 8 * 64 * 8 * 2);
    unsigned short* cW3p    = (unsigned short*)carve((size_t)13 * 4 * 64 * 8 * 2);
    float*          h       = (float*)carve((size_t)N * D * 4);
    unsigned short* xl      = (unsigned short*)carve((size_t)N * D * 2);
    unsigned short* xr      = (unsigned short*)carve((size_t)N * D * 2);
    (void)ws_size; (void)n_in; (void)out_size;

    const int ntiles16 = (N + 15) / 16;
    const int sblocks = max(ntiles16, (E + N + 255) / 256);

    init_enc_k<<<(N + 3) / 4, 256, 0, stream>>>(x, encW, encb, encls, enclb, h, deg, N);
    count_repack_k<<<512, 256, 0, stream>>>(edst, deg, E, Wl, Wr, Wp, cW1, cW1p, cW2, cW2p, cW3, cW3p);
    scan_k<<<1, 1024, 0, stream>>>(deg, row_ptr, fill, N);
    scatter_gemm0_k<<<sblocks, 256, 0, stream>>>(esrc, edst, fill, col, E, N, h,
                                                 Wp + 0, Wp + (size_t)65536,
                                                 bl + 0, br + 0, xl, xr);
    for (int l = 0; l < NL; l++) {
        attn_k<<<N, 256, 0, stream>>>(xl, xr, row_ptr, col, att + l * NH * NC,
                                      gb + l * D, gls + l * D, glb + l * D, h, l, N);
        if (l + 1 < NL) {
            gemm_k<<<ntiles16, 256, 0, stream>>>(h,
                                                 Wp + (size_t)((l + 1) * 2 + 0) * 65536,
                                                 Wp + (size_t)((l + 1) * 2 + 1) * 65536,
                                                 bl + (l + 1) * D, br + (l + 1) * D, xl, xr, N);
        }
    }
    float* out = (float*)d_out;
    color_mfma_k<<<ntiles16, 256, 0, stream>>>(h, cW1p, cb1, cW2p, cb2, cW3p, cb3, out, N);
    pool_k<<<dim3(BG, PS), 256, 0, stream>>>(h, batch, psum, pmax, cnt, N);
    heads_k<<<dim3(BG, 3), 256, 0, stream>>>(psum, pmax, cnt, chW1, chb1, chW2, chb2, chW3, chb3,
                                             tW1, tb1, tW2, tb2, dW1, db1, dW2, db2,
                                             out + (size_t)N * MC,
                                             out + (size_t)N * MC + BG * MC,
                                             out + (size_t)N * MC + BG * MC + BG * NT);
}

// Round 18
// 434.815 us; speedup vs baseline: 1.0307x; 1.0307x over previous
//
#include <hip/hip_runtime.h>
#include <hip/hip_bf16.h>

constexpr int DIN = 16;
constexpr int D   = 256;
constexpr int NH  = 8;
constexpr int NC  = 32;
constexpr int MC  = 200;
constexpr int NT  = 8;
constexpr int BG  = 16;
constexpr int NL  = 6;
constexpr int PS  = 16;   // pool slices per graph
constexpr float NEG = 0.2f;

typedef __attribute__((ext_vector_type(8))) short bfrag;
typedef __attribute__((ext_vector_type(4))) float f32x4;

__device__ inline unsigned short f2bf(float f) {
    unsigned int u = __float_as_uint(f);
    u += 0x7FFFu + ((u >> 16) & 1u);
    return (unsigned short)(u >> 16);
}
__device__ inline float bf2f(unsigned short u) {
    return __uint_as_float((unsigned int)u << 16);
}

__device__ inline float dot_ilp(const float* g, const float* __restrict__ W, int K, int ldw, int t) {
    float a0 = 0.f, a1 = 0.f, a2 = 0.f, a3 = 0.f;
    for (int k = 0; k < K; k += 4) {
        a0 = fmaf(g[k + 0], W[(k + 0) * ldw + t], a0);
        a1 = fmaf(g[k + 1], W[(k + 1) * ldw + t], a1);
        a2 = fmaf(g[k + 2], W[(k + 2) * ldw + t], a2);
        a3 = fmaf(g[k + 3], W[(k + 3) * ldw + t], a3);
    }
    return (a0 + a1) + (a2 + a3);
}

// ---------------- device helpers ----------------

__device__ inline void enc_node(const float* x, const float* W, const float* b, const float* ls,
                                const float* lb, float* h, int n, int lane) {
    int c4 = lane * 4;
    float xs[DIN];
#pragma unroll
    for (int k = 0; k < DIN; k += 4) {
        float4 xv = *(const float4*)&x[n * DIN + k];
        xs[k] = xv.x; xs[k + 1] = xv.y; xs[k + 2] = xv.z; xs[k + 3] = xv.w;
    }
    float4 a = *(const float4*)&b[c4];
#pragma unroll
    for (int k = 0; k < DIN; k++) {
        float4 wv = *(const float4*)&W[k * D + c4];
        a.x = fmaf(xs[k], wv.x, a.x);
        a.y = fmaf(xs[k], wv.y, a.y);
        a.z = fmaf(xs[k], wv.z, a.z);
        a.w = fmaf(xs[k], wv.w, a.w);
    }
    float s = a.x + a.y + a.z + a.w;
#pragma unroll
    for (int msk = 1; msk <= 32; msk <<= 1) s += __shfl_xor(s, msk);
    float mu = s * (1.f / D);
    float4 dv = make_float4(a.x - mu, a.y - mu, a.z - mu, a.w - mu);
    float v2 = dv.x * dv.x + dv.y * dv.y + dv.z * dv.z + dv.w * dv.w;
#pragma unroll
    for (int msk = 1; msk <= 32; msk <<= 1) v2 += __shfl_xor(v2, msk);
    float rstd = rsqrtf(v2 * (1.f / D) + 1e-5f);
    float4 lsv = *(const float4*)&ls[c4];
    float4 lbv = *(const float4*)&lb[c4];
    float4 y = make_float4(fmaxf(dv.x * rstd * lsv.x + lbv.x, 0.f),
                           fmaxf(dv.y * rstd * lsv.y + lbv.y, 0.f),
                           fmaxf(dv.z * rstd * lsv.z + lbv.z, 0.f),
                           fmaxf(dv.w * rstd * lsv.w + lbv.w, 0.f));
    *(float4*)&h[(size_t)n * D + c4] = y;
}

// attn for one node (one full wave); returns residual-added output (4 channels of this lane)
__device__ inline float4 attn_compute(const unsigned short* xl, const unsigned short* xr,
                                      const int* row_ptr, const int* col, const float* att,
                                      const float* gb, const float* gls, const float* glb,
                                      const float* h, int layer, int n, int lane) {
    int c4 = lane * 4;
    ushort4 xr4 = *(const ushort4*)&xr[(size_t)n * D + c4];
    float4 xrv = make_float4(bf2f(xr4.x), bf2f(xr4.y), bf2f(xr4.z), bf2f(xr4.w));
    float4 av  = *(const float4*)&att[c4];
    int beg = row_ptr[n], end = row_ptr[n + 1];
    int deg = end - beg;
    int myc = col[beg + min(lane, deg - 1)];
    float m = -3.0e38f, l = 0.f;
    float4 acc = make_float4(0.f, 0.f, 0.f, 0.f);
    auto loadx = [&](int i) -> ushort4 {
        if (i < deg) {
            int s = (i < 64) ? __shfl(myc, i) : col[beg + i];
            return *(const ushort4*)&xl[(size_t)s * D + c4];
        }
        return make_ushort4(0, 0, 0, 0);
    };
    auto step = [&](ushort4 x4) {
        float4 xlv = make_float4(bf2f(x4.x), bf2f(x4.y), bf2f(x4.z), bf2f(x4.w));
        float sx = xlv.x + xrv.x; sx = sx > 0.f ? sx : NEG * sx;
        float sy = xlv.y + xrv.y; sy = sy > 0.f ? sy : NEG * sy;
        float sz = xlv.z + xrv.z; sz = sz > 0.f ? sz : NEG * sz;
        float sw = xlv.w + xrv.w; sw = sw > 0.f ? sw : NEG * sw;
        float z = av.x * sx + av.y * sy + av.z * sz + av.w * sw;
        z += __shfl_xor(z, 1); z += __shfl_xor(z, 2); z += __shfl_xor(z, 4);
        float mn = fmaxf(m, z);
        float sc = __expf(m - mn);
        float p  = __expf(z - mn);
        l = l * sc + p;
        acc.x = acc.x * sc + p * xlv.x;
        acc.y = acc.y * sc + p * xlv.y;
        acc.z = acc.z * sc + p * xlv.z;
        acc.w = acc.w * sc + p * xlv.w;
        m = mn;
    };
    ushort4 b0 = loadx(0), b1 = loadx(1), b2 = loadx(2), b3 = loadx(3);
    int e = 0;
    for (; e + 4 <= deg; e += 4) {
        ushort4 n0 = loadx(e + 4), n1 = loadx(e + 5), n2 = loadx(e + 6), n3 = loadx(e + 7);
        step(b0); step(b1); step(b2); step(b3);
        b0 = n0; b1 = n1; b2 = n2; b3 = n3;
    }
    if (e + 0 < deg) step(b0);
    if (e + 1 < deg) step(b1);
    if (e + 2 < deg) step(b2);
    float4 gbv = *(const float4*)&gb[c4];
    float rl = 1.f / l;
    float4 o = make_float4(acc.x * rl + gbv.x, acc.y * rl + gbv.y,
                           acc.z * rl + gbv.z, acc.w * rl + gbv.w);
    float s = o.x + o.y + o.z + o.w;
#pragma unroll
    for (int msk = 1; msk <= 32; msk <<= 1) s += __shfl_xor(s, msk);
    float mu = s * (1.f / D);
    float4 dv = make_float4(o.x - mu, o.y - mu, o.z - mu, o.w - mu);
    float v2 = dv.x * dv.x + dv.y * dv.y + dv.z * dv.z + dv.w * dv.w;
#pragma unroll
    for (int msk = 1; msk <= 32; msk <<= 1) v2 += __shfl_xor(v2, msk);
    float rstd = rsqrtf(v2 * (1.f / D) + 1e-5f);
    float4 glsv = *(const float4*)&gls[c4];
    float4 glbv = *(const float4*)&glb[c4];
    float y0 = dv.x * rstd * glsv.x + glbv.x;
    float y1 = dv.y * rstd * glsv.y + glbv.y;
    float y2 = dv.z * rstd * glsv.z + glbv.z;
    float y3 = dv.w * rstd * glsv.w + glbv.w;
    y0 = y0 > 0.f ? y0 : expm1f(y0);
    y1 = y1 > 0.f ? y1 : expm1f(y1);
    y2 = y2 > 0.f ? y2 : expm1f(y2);
    y3 = y3 > 0.f ? y3 : expm1f(y3);
    float4 prev = make_float4(0.f, 0.f, 0.f, 0.f);
    if (layer > 0) prev = *(const float4*)&h[(size_t)n * D + c4];
    return make_float4(prev.x + y0, prev.y + y1, prev.z + y2, prev.w + y3);
}

// TWO interleaved attention chains per wave (nodes n0 valid, n1 optional).
__device__ inline void attn2(const unsigned short* xl, const unsigned short* xr,
                             const int* row_ptr, const int* col, const float* att,
                             const float* gb, const float* gls, const float* glb,
                             const float* h, int layer, int n0, int n1, int N, int lane,
                             float4& out0, float4& out1) {
    int c4 = lane * 4;
    float4 av = *(const float4*)&att[c4];
    bool v1 = (n1 < N);
    ushort4 x40 = *(const ushort4*)&xr[(size_t)n0 * D + c4];
    float4 xrv0 = make_float4(bf2f(x40.x), bf2f(x40.y), bf2f(x40.z), bf2f(x40.w));
    float4 xrv1 = make_float4(0.f, 0.f, 0.f, 0.f);
    if (v1) {
        ushort4 x41 = *(const ushort4*)&xr[(size_t)n1 * D + c4];
        xrv1 = make_float4(bf2f(x41.x), bf2f(x41.y), bf2f(x41.z), bf2f(x41.w));
    }
    int beg0 = row_ptr[n0], deg0 = row_ptr[n0 + 1] - beg0;
    int beg1 = v1 ? row_ptr[n1] : 0;
    int deg1 = v1 ? (row_ptr[n1 + 1] - beg1) : 0;
    int myc0 = col[beg0 + min(lane, deg0 - 1)];
    int myc1 = v1 ? col[beg1 + min(lane, deg1 - 1)] : 0;
    float m0 = -3.0e38f, l0 = 0.f, m1 = -3.0e38f, l1 = 0.f;
    float4 a0 = make_float4(0.f, 0.f, 0.f, 0.f);
    float4 a1 = make_float4(0.f, 0.f, 0.f, 0.f);
    auto load0 = [&](int i) -> ushort4 {
        if (i < deg0) {
            int s = (i < 64) ? __shfl(myc0, i) : col[beg0 + i];
            return *(const ushort4*)&xl[(size_t)s * D + c4];
        }
        return make_ushort4(0, 0, 0, 0);
    };
    auto load1 = [&](int i) -> ushort4 {
        if (i < deg1) {
            int s = (i < 64) ? __shfl(myc1, i) : col[beg1 + i];
            return *(const ushort4*)&xl[(size_t)s * D + c4];
        }
        return make_ushort4(0, 0, 0, 0);
    };
    auto step0 = [&](ushort4 x4) {
        float4 xlv = make_float4(bf2f(x4.x), bf2f(x4.y), bf2f(x4.z), bf2f(x4.w));
        float sx = xlv.x + xrv0.x; sx = sx > 0.f ? sx : NEG * sx;
        float sy = xlv.y + xrv0.y; sy = sy > 0.f ? sy : NEG * sy;
        float sz = xlv.z + xrv0.z; sz = sz > 0.f ? sz : NEG * sz;
        float sw = xlv.w + xrv0.w; sw = sw > 0.f ? sw : NEG * sw;
        float z = av.x * sx + av.y * sy + av.z * sz + av.w * sw;
        z += __shfl_xor(z, 1); z += __shfl_xor(z, 2); z += __shfl_xor(z, 4);
        float mn = fmaxf(m0, z);
        float sc = __expf(m0 - mn);
        float p  = __expf(z - mn);
        l0 = l0 * sc + p;
        a0.x = a0.x * sc + p * xlv.x;
        a0.y = a0.y * sc + p * xlv.y;
        a0.z = a0.z * sc + p * xlv.z;
        a0.w = a0.w * sc + p * xlv.w;
        m0 = mn;
    };
    auto step1 = [&](ushort4 x4) {
        float4 xlv = make_float4(bf2f(x4.x), bf2f(x4.y), bf2f(x4.z), bf2f(x4.w));
        float sx = xlv.x + xrv1.x; sx = sx > 0.f ? sx : NEG * sx;
        float sy = xlv.y + xrv1.y; sy = sy > 0.f ? sy : NEG * sy;
        float sz = xlv.z + xrv1.z; sz = sz > 0.f ? sz : NEG * sz;
        float sw = xlv.w + xrv1.w; sw = sw > 0.f ? sw : NEG * sw;
        float z = av.x * sx + av.y * sy + av.z * sz + av.w * sw;
        z += __shfl_xor(z, 1); z += __shfl_xor(z, 2); z += __shfl_xor(z, 4);
        float mn = fmaxf(m1, z);
        float sc = __expf(m1 - mn);
        float p  = __expf(z - mn);
        l1 = l1 * sc + p;
        a1.x = a1.x * sc + p * xlv.x;
        a1.y = a1.y * sc + p * xlv.y;
        a1.z = a1.z * sc + p * xlv.z;
        a1.w = a1.w * sc + p * xlv.w;
        m1 = mn;
    };
    ushort4 p00 = load0(0), p01 = load0(1), p10 = load1(0), p11 = load1(1);
    int mx = max(deg0, deg1);
    for (int e = 0; e < mx; e += 2) {
        ushort4 q00 = load0(e + 2), q01 = load0(e + 3);
        ushort4 q10 = load1(e + 2), q11 = load1(e + 3);
        if (e < deg0) step0(p00);
        if (e < deg1) step1(p10);
        if (e + 1 < deg0) step0(p01);
        if (e + 1 < deg1) step1(p11);
        p00 = q00; p01 = q01; p10 = q10; p11 = q11;
    }
    float4 gbv = *(const float4*)&gb[c4];
    float4 glsv = *(const float4*)&gls[c4];
    float4 glbv = *(const float4*)&glb[c4];
    auto epilogue = [&](float4 acc, float l, int n) -> float4 {
        float rl = 1.f / l;
        float4 o = make_float4(acc.x * rl + gbv.x, acc.y * rl + gbv.y,
                               acc.z * rl + gbv.z, acc.w * rl + gbv.w);
        float s = o.x + o.y + o.z + o.w;
#pragma unroll
        for (int msk = 1; msk <= 32; msk <<= 1) s += __shfl_xor(s, msk);
        float mu = s * (1.f / D);
        float4 dv = make_float4(o.x - mu, o.y - mu, o.z - mu, o.w - mu);
        float v2 = dv.x * dv.x + dv.y * dv.y + dv.z * dv.z + dv.w * dv.w;
#pragma unroll
        for (int msk = 1; msk <= 32; msk <<= 1) v2 += __shfl_xor(v2, msk);
        float rstd = rsqrtf(v2 * (1.f / D) + 1e-5f);
        float y0 = dv.x * rstd * glsv.x + glbv.x;
        float y1 = dv.y * rstd * glsv.y + glbv.y;
        float y2 = dv.z * rstd * glsv.z + glbv.z;
        float y3 = dv.w * rstd * glsv.w + glbv.w;
        y0 = y0 > 0.f ? y0 : expm1f(y0);
        y1 = y1 > 0.f ? y1 : expm1f(y1);
        y2 = y2 > 0.f ? y2 : expm1f(y2);
        y3 = y3 > 0.f ? y3 : expm1f(y3);
        float4 prev = make_float4(0.f, 0.f, 0.f, 0.f);
        if (layer > 0) prev = *(const float4*)&h[(size_t)n * D + c4];
        return make_float4(prev.x + y0, prev.y + y1, prev.z + y2, prev.w + y3);
    };
    out0 = epilogue(a0, l0, n0);
    if (v1) out1 = epilogue(a1, l1, n1);
    else    out1 = make_float4(0.f, 0.f, 0.f, 0.f);
}

// MFMA GEMM on a 16-row tile, executed by ONE wave handling ONE 16-col tile (ctg).
__device__ inline void gemm_one_ct(const unsigned short (*As)[264],
                                   const unsigned short* WpL, const unsigned short* WpR,
                                   const float* bl, const float* br,
                                   unsigned short* xl, unsigned short* xr,
                                   int N, int nb, int ctg, int lane) {
    int m = lane & 15, q = lane >> 4;
    float bLv = bl[ctg * 16 + m];
    float bRv = br[ctg * 16 + m];
    f32x4 accL = (f32x4){bLv, bLv, bLv, bLv};
    f32x4 accR = (f32x4){bRv, bRv, bRv, bRv};
#pragma unroll
    for (int ks = 0; ks < 8; ks++) {
        bfrag af = *(const bfrag*)&As[m][ks * 32 + q * 8];
        size_t off = (((size_t)ctg * 8 + ks) * 64 + lane) * 8;
        bfrag bL = *(const bfrag*)&WpL[off];
        bfrag bR = *(const bfrag*)&WpR[off];
        accL = __builtin_amdgcn_mfma_f32_16x16x32_bf16(af, bL, accL, 0, 0, 0);
        accR = __builtin_amdgcn_mfma_f32_16x16x32_bf16(af, bR, accR, 0, 0, 0);
    }
    int colg = ctg * 16 + m;
#pragma unroll
    for (int reg = 0; reg < 4; reg++) {
        int row = nb + q * 4 + reg;
        if (row < N) {
            xl[(size_t)row * D + colg] = f2bf(accL[reg]);
            xr[(size_t)row * D + colg] = f2bf(accR[reg]);
        }
    }
}

// 4-wave variant (wave w owns col-tiles w*4..w*4+3) — used by scatter_gemm0_k
__device__ inline void gemm_core(const unsigned short (*As)[264],
                                 const unsigned short* WpL, const unsigned short* WpR,
                                 const float* bl, const float* br,
                                 unsigned short* xl, unsigned short* xr, int N, int nb, int T) {
    int lane = T & 63, w = T >> 6;
#pragma unroll
    for (int ct = 0; ct < 4; ct++)
        gemm_one_ct(As, WpL, WpR, bl, br, xl, xr, N, nb, w * 4 + ct, lane);
}

__device__ inline void repack_attn_one(const float* Wl, const float* Wr, unsigned short* Wp, int tid) {
    int lane = tid & 63;
    int r1 = tid >> 6;
    int ks = r1 & 7;
    int r2 = r1 >> 3;
    int ct = r2 & 15;
    int mi = r2 >> 4;
    int layer = mi >> 1, mat = mi & 1;
    const float* W = (mat == 0 ? Wl : Wr) + (size_t)layer * D * D;
    int n = ct * 16 + (lane & 15);
    int kb = ks * 32 + (lane >> 4) * 8;
    size_t base = (((size_t)(mi * 16 + ct) * 8 + ks) * 64 + lane) * 8;
#pragma unroll
    for (int j = 0; j < 8; j++) Wp[base + j] = f2bf(W[(size_t)(kb + j) * D + n]);
}

__device__ inline void repack_gen_one(const float* W, unsigned short* Wp, int K, int NCOL, int nks, int tid) {
    int lane = tid & 63;
    int r = tid >> 6;
    int ks = r % nks;
    int ct = r / nks;
    int n = ct * 16 + (lane & 15);
    int kb = ks * 32 + (lane >> 4) * 8;
    size_t base = (((size_t)ct * nks + ks) * 64 + lane) * 8;
#pragma unroll
    for (int j = 0; j < 8; j++) {
        int k = kb + j;
        Wp[base + j] = (n < NCOL && k < K) ? f2bf(W[(size_t)k * NCOL + n]) : (unsigned short)0;
    }
}

// ---------------- kernels (12 dispatches) ----------------

// d1: deg=1 + encoder (wave per node)
__global__ __launch_bounds__(256) void init_enc_k(const float* __restrict__ x, const float* __restrict__ W,
                                                  const float* __restrict__ b, const float* __restrict__ ls,
                                                  const float* __restrict__ lb, float* __restrict__ h,
                                                  int* __restrict__ deg, int N) {
    int gid = blockIdx.x * 256 + threadIdx.x;
    if (gid < N) deg[gid] = 1;
    int lane = threadIdx.x & 63;
    int n = blockIdx.x * 4 + (threadIdx.x >> 6);
    if (n < N) enc_node(x, W, b, ls, lb, h, n, lane);
}

// d2: edge count + all weight repacks
__global__ __launch_bounds__(256) void count_repack_k(const int* __restrict__ dst, int* __restrict__ deg, int E,
                                                      const float* __restrict__ Wl, const float* __restrict__ Wr,
                                                      unsigned short* __restrict__ Wp,
                                                      const float* __restrict__ cW1, unsigned short* __restrict__ cW1p,
                                                      const float* __restrict__ cW2, unsigned short* __restrict__ cW2p,
                                                      const float* __restrict__ cW3, unsigned short* __restrict__ cW3p) {
    int gid = blockIdx.x * 256 + threadIdx.x;
    if (gid < E) atomicAdd(&deg[dst[gid]], 1);
    if (gid < NL * 2 * 16 * 8 * 64) repack_attn_one(Wl, Wr, Wp, gid);
    if (gid < 16 * 8 * 64) repack_gen_one(cW1, cW1p, D, D, 8, gid);
    if (gid < 8 * 8 * 64)  repack_gen_one(cW2, cW2p, D, 128, 8, gid);
    if (gid < 13 * 4 * 64) repack_gen_one(cW3, cW3p, 128, MC, 4, gid);
}

// d3: single-block scan
__global__ __launch_bounds__(1024) void scan_k(const int* __restrict__ deg, int* __restrict__ row_ptr,
                                               int* __restrict__ fill, int N) {
    __shared__ int sd[1024];
    int t = threadIdx.x;
    int chunk = (N + 1023) >> 10;
    int lo = t * chunk, hi = min(lo + chunk, N);
    int s = 0;
    for (int i = lo; i < hi; i++) s += deg[i];
    sd[t] = s;
    __syncthreads();
    for (int off = 1; off < 1024; off <<= 1) {
        int v = (t >= off) ? sd[t - off] : 0;
        __syncthreads();
        sd[t] += v;
        __syncthreads();
    }
    int run = (t > 0) ? sd[t - 1] : 0;
    for (int i = lo; i < hi; i++) {
        row_ptr[i] = run; fill[i] = run;
        run += deg[i];
    }
    if (t == 1023) row_ptr[N] = sd[1023];
}

// d4: scatter + layer-0 GEMM
__global__ __launch_bounds__(256) void scatter_gemm0_k(const int* __restrict__ src, const int* __restrict__ dst,
                                                       int* __restrict__ fill, int* __restrict__ col, int E, int N,
                                                       const float* __restrict__ h,
                                                       const unsigned short* __restrict__ WpL,
                                                       const unsigned short* __restrict__ WpR,
                                                       const float* __restrict__ bl, const float* __restrict__ br,
                                                       unsigned short* __restrict__ xl, unsigned short* __restrict__ xr) {
    __shared__ unsigned short As[16][264];
    int T = threadIdx.x;
    int tt = blockIdx.x;
    int ntiles = (N + 15) >> 4;
    if (tt < ntiles) {
        int nb = tt * 16;
#pragma unroll
        for (int r = 0; r < 16; r++) {
            int row = nb + r;
            float v = (row < N) ? h[(size_t)row * D + T] : 0.f;
            As[r][T] = f2bf(v);
        }
        __syncthreads();
        gemm_core(As, WpL, WpR, bl, br, xl, xr, N, nb, T);
    }
    for (int e = blockIdx.x * 256 + T; e < E + N; e += gridDim.x * 256) {
        if (e < E) {
            int p = atomicAdd(&fill[dst[e]], 1);
            col[p] = src[e];
        } else {
            int n = e - E;
            int p = atomicAdd(&fill[n], 1);
            col[p] = n;
        }
    }
}

// d5..d9: fused attn(l) + gemm(l+1). 1024 threads = 16 waves; TWO nodes per wave (32 nodes/block).
__global__ __launch_bounds__(1024, 4) void layer_k(const unsigned short* __restrict__ xl_in,
                                                   const unsigned short* __restrict__ xr_in,
                                                   const int* __restrict__ row_ptr, const int* __restrict__ col,
                                                   const float* __restrict__ att, const float* __restrict__ gb,
                                                   const float* __restrict__ gls, const float* __restrict__ glb,
                                                   float* __restrict__ h, int layer, int N,
                                                   const unsigned short* __restrict__ WpL,
                                                   const unsigned short* __restrict__ WpR,
                                                   const float* __restrict__ bl, const float* __restrict__ br,
                                                   unsigned short* __restrict__ xl_out, unsigned short* __restrict__ xr_out) {
    __shared__ unsigned short As[32][264];
    int T = threadIdx.x;
    int lane = T & 63, wv = T >> 6;       // wv in [0,16)
    int nb = blockIdx.x * 32;
    int c4 = lane * 4;
    int n0 = nb + wv, n1 = nb + wv + 16;
    if (n0 < N) {
        float4 r0, r1;
        attn2(xl_in, xr_in, row_ptr, col, att, gb, gls, glb, h, layer, n0, n1, N, lane, r0, r1);
        *(float4*)&h[(size_t)n0 * D + c4] = r0;
        As[wv][c4 + 0] = f2bf(r0.x);
        As[wv][c4 + 1] = f2bf(r0.y);
        As[wv][c4 + 2] = f2bf(r0.z);
        As[wv][c4 + 3] = f2bf(r0.w);
        if (n1 < N) {
            *(float4*)&h[(size_t)n1 * D + c4] = r1;
            As[wv + 16][c4 + 0] = f2bf(r1.x);
            As[wv + 16][c4 + 1] = f2bf(r1.y);
            As[wv + 16][c4 + 2] = f2bf(r1.z);
            As[wv + 16][c4 + 3] = f2bf(r1.w);
        } else {
            As[wv + 16][c4 + 0] = 0; As[wv + 16][c4 + 1] = 0;
            As[wv + 16][c4 + 2] = 0; As[wv + 16][c4 + 3] = 0;
        }
    } else {
        As[wv][c4 + 0] = 0; As[wv][c4 + 1] = 0; As[wv][c4 + 2] = 0; As[wv][c4 + 3] = 0;
        As[wv + 16][c4 + 0] = 0; As[wv + 16][c4 + 1] = 0;
        As[wv + 16][c4 + 2] = 0; As[wv + 16][c4 + 3] = 0;
    }
    __syncthreads();
    gemm_one_ct((const unsigned short (*)[264])&As[0],  WpL, WpR, bl, br, xl_out, xr_out, N, nb,      wv, lane);
    gemm_one_ct((const unsigned short (*)[264])&As[16], WpL, WpR, bl, br, xl_out, xr_out, N, nb + 16, wv, lane);
}

// d10: final attn (layer 5) + fused color-head MFMA MLP (1024 threads, 16 nodes/block)
__global__ __launch_bounds__(1024) void last_k(const unsigned short* __restrict__ xl_in,
                                               const unsigned short* __restrict__ xr_in,
                                               const int* __restrict__ row_ptr, const int* __restrict__ col,
                                               const float* __restrict__ att, const float* __restrict__ gb,
                                               const float* __restrict__ gls, const float* __restrict__ glb,
                                               float* __restrict__ h, int N,
                                               const unsigned short* __restrict__ W1p, const float* __restrict__ b1,
                                               const unsigned short* __restrict__ W2p, const float* __restrict__ b2,
                                               const unsigned short* __restrict__ W3p, const float* __restrict__ b3,
                                               float* __restrict__ out) {
    __shared__ unsigned short As[16][264];
    __shared__ unsigned short Zs[16][264];
    int T = threadIdx.x;
    int lane = T & 63, wv = T >> 6;
    int nb = blockIdx.x * 16;
    int c4 = lane * 4;
    int n = nb + wv;
    if (n < N) {
        float4 res = attn_compute(xl_in, xr_in, row_ptr, col, att, gb, gls, glb, h, NL - 1, n, lane);
        *(float4*)&h[(size_t)n * D + c4] = res;
        As[wv][c4 + 0] = f2bf(res.x);
        As[wv][c4 + 1] = f2bf(res.y);
        As[wv][c4 + 2] = f2bf(res.z);
        As[wv][c4 + 3] = f2bf(res.w);
    } else {
        As[wv][c4 + 0] = 0; As[wv][c4 + 1] = 0; As[wv][c4 + 2] = 0; As[wv][c4 + 3] = 0;
    }
    __syncthreads();
    int m = lane & 15, q = lane >> 4;
    {
        float bv = b1[wv * 16 + m];
        f32x4 acc = (f32x4){bv, bv, bv, bv};
#pragma unroll
        for (int ks = 0; ks < 8; ks++) {
            bfrag af = *(const bfrag*)&As[m][ks * 32 + q * 8];
            bfrag bf = *(const bfrag*)&W1p[(((size_t)wv * 8 + ks) * 64 + lane) * 8];
            acc = __builtin_amdgcn_mfma_f32_16x16x32_bf16(af, bf, acc, 0, 0, 0);
        }
        int colg = wv * 16 + m;
#pragma unroll
        for (int reg = 0; reg < 4; reg++)
            Zs[q * 4 + reg][colg] = f2bf(fmaxf(acc[reg], 0.f));
    }
    __syncthreads();
    if (wv < 8) {
        float bv = b2[wv * 16 + m];
        f32x4 acc = (f32x4){bv, bv, bv, bv};
#pragma unroll
        for (int ks = 0; ks < 8; ks++) {
            bfrag af = *(const bfrag*)&Zs[m][ks * 32 + q * 8];
            bfrag bf = *(const bfrag*)&W2p[(((size_t)wv * 8 + ks) * 64 + lane) * 8];
            acc = __builtin_amdgcn_mfma_f32_16x16x32_bf16(af, bf, acc, 0, 0, 0);
        }
        int colg = wv * 16 + m;
#pragma unroll
        for (int reg = 0; reg < 4; reg++)
            As[q * 4 + reg][colg] = f2bf(fmaxf(acc[reg], 0.f));
    }
    __syncthreads();
    if (wv < 13) {
        int colg = wv * 16 + m;
        float bv = (colg < MC) ? b3[colg] : 0.f;
        f32x4 acc = (f32x4){bv, bv, bv, bv};
#pragma unroll
        for (int ks = 0; ks < 4; ks++) {
            bfrag af = *(const bfrag*)&As[m][ks * 32 + q * 8];
            bfrag bf = *(const bfrag*)&W3p[(((size_t)wv * 4 + ks) * 64 + lane) * 8];
            acc = __builtin_amdgcn_mfma_f32_16x16x32_bf16(af, bf, acc, 0, 0, 0);
        }
#pragma unroll
        for (int reg = 0; reg < 4; reg++) {
            int row = nb + q * 4 + reg;
            if (row < N && colg < MC) out[(size_t)row * MC + colg] = acc[reg];
        }
    }
}

// d11: pooling stage 1
__global__ __launch_bounds__(256) void pool_k(const float* __restrict__ h, const int* __restrict__ batch,
                                              float* __restrict__ psum, float* __restrict__ pmax,
                                              int* __restrict__ cnt, int N) {
    int b = blockIdx.x;
    int sl = blockIdx.y;
    int c = threadIdx.x;
    int lo = 0, hi = N;
    while (lo < hi) { int mid = (lo + hi) >> 1; if (batch[mid] < b) lo = mid + 1; else hi = mid; }
    int s0 = lo;
    lo = 0; hi = N;
    while (lo < hi) { int mid = (lo + hi) >> 1; if (batch[mid] < b + 1) lo = mid + 1; else hi = mid; }
    int s1 = lo;
    int len = s1 - s0;
    int chunk = (len + PS - 1) / PS;
    int n0 = s0 + sl * chunk;
    int n1 = min(n0 + chunk, s1);
    float sum = 0.f, mx = -3.0e38f;
    for (int n = n0; n < n1; n++) {
        float v = h[(size_t)n * D + c];
        sum += v;
        mx = fmaxf(mx, v);
    }
    psum[(size_t)(b * PS + sl) * D + c] = sum;
    pmax[(size_t)(b * PS + sl) * D + c] = mx;
    if (c == 0 && sl == 0) cnt[b] = len;
}

// d12: graph heads
__global__ __launch_bounds__(256) void heads_k(const float* __restrict__ psum, const float* __restrict__ pmax,
                                               const int* __restrict__ cnt,
                                               const float* __restrict__ chW1, const float* __restrict__ chb1,
                                               const float* __restrict__ chW2, const float* __restrict__ chb2,
                                               const float* __restrict__ chW3, const float* __restrict__ chb3,
                                               const float* __restrict__ tW1, const float* __restrict__ tb1,
                                               const float* __restrict__ tW2, const float* __restrict__ tb2,
                                               const float* __restrict__ dW1, const float* __restrict__ db1,
                                               const float* __restrict__ dW2, const float* __restrict__ db2,
                                               float* __restrict__ out_ch, float* __restrict__ out_t,
                                               float* __restrict__ out_d) {
    int b = blockIdx.x, sec = blockIdx.y, t = threadIdx.x;
    __shared__ float g[2 * D];
    __shared__ float z1[D];
    __shared__ float z2[128];
    float sum = 0.f, mx = -3.0e38f;
#pragma unroll
    for (int sl = 0; sl < PS; sl++) {
        sum += psum[(size_t)(b * PS + sl) * D + t];
        mx = fmaxf(mx, pmax[(size_t)(b * PS + sl) * D + t]);
    }
    int cn = cnt[b];
    float c = fmaxf((float)cn, 1.f);
    g[t] = sum / c;
    g[D + t] = (cn > 0) ? mx : 0.f;
    __syncthreads();
    if (sec == 0) {
        z1[t] = fmaxf(chb1[t] + dot_ilp(g, chW1, 2 * D, D, t), 0.f);
        __syncthreads();
        if (t < 128) z2[t] = fmaxf(chb2[t] + dot_ilp(z1, chW2, D, 128, t), 0.f);
        __syncthreads();
        if (t < MC) out_ch[b * MC + t] = chb3[t] + dot_ilp(z2, chW3, 128, MC, t);
    } else if (sec == 1) {
        if (t < 128) z1[t] = fmaxf(tb1[t] + dot_ilp(g, tW1, 2 * D, 128, t), 0.f);
        __syncthreads();
        if (t < NT) out_t[b * NT + t] = tb2[t] + dot_ilp(z1, tW2, 128, NT, t);
    } else {
        if (t < 64) z1[t] = fmaxf(db1[t] + dot_ilp(g, dW1, 2 * D, 64, t), 0.f);
        __syncthreads();
        if (t == 0) {
            float a = db2[0] + dot_ilp(z1, dW2, 64, 1, 0);
            out_d[b] = 100.f / (1.f + __expf(-a));
        }
    }
}

// ----------------------------------------------------------------
extern "C" void kernel_launch(void* const* d_in, const int* in_sizes, int n_in,
                              void* d_out, int out_size, void* d_ws, size_t ws_size,
                              hipStream_t stream) {
    const float* x     = (const float*)d_in[0];
    const int*   ei    = (const int*)d_in[1];
    const int*   batch = (const int*)d_in[2];
    const float* encW  = (const float*)d_in[3];
    const float* encb  = (const float*)d_in[4];
    const float* encls = (const float*)d_in[5];
    const float* enclb = (const float*)d_in[6];
    const float* Wl    = (const float*)d_in[7];
    const float* bl    = (const float*)d_in[8];
    const float* Wr    = (const float*)d_in[9];
    const float* br    = (const float*)d_in[10];
    const float* att   = (const float*)d_in[11];
    const float* gb    = (const float*)d_in[12];
    const float* gls   = (const float*)d_in[13];
    const float* glb   = (const float*)d_in[14];
    const float* cW1   = (const float*)d_in[15];
    const float* cb1   = (const float*)d_in[16];
    const float* cW2   = (const float*)d_in[17];
    const float* cb2   = (const float*)d_in[18];
    const float* cW3   = (const float*)d_in[19];
    const float* cb3   = (const float*)d_in[20];
    const float* chW1  = (const float*)d_in[21];
    const float* chb1  = (const float*)d_in[22];
    const float* chW2  = (const float*)d_in[23];
    const float* chb2  = (const float*)d_in[24];
    const float* chW3  = (const float*)d_in[25];
    const float* chb3  = (const float*)d_in[26];
    const float* tW1   = (const float*)d_in[27];
    const float* tb1   = (const float*)d_in[28];
    const float* tW2   = (const float*)d_in[29];
    const float* tb2   = (const float*)d_in[30];
    const float* dW1   = (const float*)d_in[31];
    const float* db1   = (const float*)d_in[32];
    const float* dW2   = (const float*)d_in[33];
    const float* db2   = (const float*)d_in[34];

    const int N = in_sizes[0] / DIN;
    const int E = in_sizes[1] / 2;
    const int* esrc = ei;
    const int* edst = ei + E;

    char* p = (char*)d_ws;
    auto carve = [&](size_t bytes) { char* r = p; p += (bytes + 255) & ~(size_t)255; return r; };
    int*            row_ptr = (int*)carve((size_t)(N + 1) * 4);
    int*            fill    = (int*)carve((size_t)N * 4);
    int*            deg     = (int*)carve((size_t)N * 4);
    int*            cnt     = (int*)carve((size_t)BG * 4);
    float*          psum    = (float*)carve((size_t)BG * PS * D * 4);
    float*          pmax    = (float*)carve((size_t)BG * PS * D * 4);
    int*            col     = (int*)carve((size_t)(E + N) * 4);
    unsigned short* Wp      = (unsigned short*)carve((size_t)NL * 2 * 65536 * 2);
    unsigned short* cW1p    = (unsigned short*)carve((size_t)16 * 8 * 64 * 8 * 2);
    unsigned short* cW2p    = (unsigned short*)carve((size_t)8 * 8 * 64 * 8 * 2);
    unsigned short* cW3p    = (unsigned short*)carve((size_t)13 * 4 * 64 * 8 * 2);
    float*          h       = (float*)carve((size_t)N * D * 4);
    unsigned short* xlA     = (unsigned short*)carve((size_t)N * D * 2);
    unsigned short* xrA     = (unsigned short*)carve((size_t)N * D * 2);
    unsigned short* xlB     = (unsigned short*)carve((size_t)N * D * 2);
    unsigned short* xrB     = (unsigned short*)carve((size_t)N * D * 2);
    (void)ws_size; (void)n_in; (void)out_size;

    const int ntiles16 = (N + 15) / 16;
    const int ntiles32 = (N + 31) / 32;
    const int sblocks = max(ntiles16, (E + N + 255) / 256);

    init_enc_k<<<(N + 3) / 4, 256, 0, stream>>>(x, encW, encb, encls, enclb, h, deg, N);
    count_repack_k<<<512, 256, 0, stream>>>(edst, deg, E, Wl, Wr, Wp, cW1, cW1p, cW2, cW2p, cW3, cW3p);
    scan_k<<<1, 1024, 0, stream>>>(deg, row_ptr, fill, N);
    scatter_gemm0_k<<<sblocks, 256, 0, stream>>>(esrc, edst, fill, col, E, N, h,
                                                 Wp + 0, Wp + (size_t)65536,
                                                 bl + 0, br + 0, xlA, xrA);
    for (int l = 0; l < NL - 1; l++) {
        const unsigned short* xin_l = (l & 1) ? xlB : xlA;
        const unsigned short* xin_r = (l & 1) ? xrB : xrA;
        unsigned short* xout_l = (l & 1) ? xlA : xlB;
        unsigned short* xout_r = (l & 1) ? xrA : xrB;
        layer_k<<<ntiles32, 1024, 0, stream>>>(xin_l, xin_r, row_ptr, col, att + l * NH * NC,
                                               gb + l * D, gls + l * D, glb + l * D, h, l, N,
                                               Wp + (size_t)((l + 1) * 2 + 0) * 65536,
                                               Wp + (size_t)((l + 1) * 2 + 1) * 65536,
                                               bl + (l + 1) * D, br + (l + 1) * D, xout_l, xout_r);
    }
    float* out = (float*)d_out;
    last_k<<<ntiles16, 1024, 0, stream>>>(xlB, xrB, row_ptr, col, att + (NL - 1) * NH * NC,
                                          gb + (NL - 1) * D, gls + (NL - 1) * D, glb + (NL - 1) * D, h, N,
                                          cW1p, cb1, cW2p, cb2, cW3p, cb3, out);
    pool_k<<<dim3(BG, PS), 256, 0, stream>>>(h, batch, psum, pmax, cnt, N);
    heads_k<<<dim3(BG, 3), 256, 0, stream>>>(psum, pmax, cnt, chW1, chb1, chW2, chb2, chW3, chb3,
                                             tW1, tb1, tW2, tb2, dW1, db1, dW2, db2,
                                             out + (size_t)N * MC,
                                             out + (size_t)N * MC + BG * MC,
                                             out + (size_t)N * MC + BG * MC + BG * NT);
}